// Round 11
// baseline (17.531 us; speedup 1.0000x reference)
//
#include <hip/hip_runtime.h>
#include <hip/hip_fp16.h>

// ComplexMixture: B=32, S=128, N=256
// Or[b,n,m] = sum_s w[b,s]*(r[b,s,n]*r[b,s,m] + i[b,s,n]*i[b,s,m])
// Oi[b,n,m] = sum_s w[b,s]*(i[b,s,n]*r[b,s,m] - r[b,s,n]*i[b,s,m])
//
// R11: 32x32 wave-tiles (2ns x 2ms of 16x16x32) to cut LDS fragment traffic
// from 0.75 to 0.5 KB/MFMA (R10's dominant cost: 448 -> 256 KB/CU).
// Block = 128n x 64m: A-side (both n-chunks, weighted) staged once by
// waves 0-3; B-side by waves 4-7. 256 blocks x 512 threads, LDS 96 KB,
// 1 block/CU. R9-proven: K-half pipeline (2 barriers), swizzle
// slot = chunk ^ ((row>>1)&7) (conflict-free b128 writes, 2-way-free reads),
// ms-split tail stores, setprio around MFMA, XCD-grouped bid swizzle.

constexpr int B = 32, S = 128, N = 256;

typedef _Float16 f16x8 __attribute__((ext_vector_type(8)));
typedef float    f32x4 __attribute__((ext_vector_type(4)));

union F16x8 { f16x8 v; __half2 h2[4]; };

#define MFMA16(a, bv, c) __builtin_amdgcn_mfma_f32_16x16x32_f16((a), (bv), (c), 0, 0, 0)

__global__ __launch_bounds__(512, 2) void ComplexMixture_71313636983193_kernel(
    const float* __restrict__ R, const float* __restrict__ I,
    const float* __restrict__ W, float* __restrict__ Or, float* __restrict__ Oi)
{
    // AW[0]=w*r, AW[1]=w*i over n-rows 0..127; Bt[0]=r, Bt[1]=i over m-rows.
    // row x, logical chunk c (8 s) at slot c ^ ((x>>1)&7).
    __shared__ alignas(16) _Float16 AW[2][128][128];  // 64 KB
    __shared__ alignas(16) _Float16 Bt[2][64][128];   // 32 KB

    const int pb   = blockIdx.x;
    const int lbid = (pb & 7) * 32 + (pb >> 3);   // 4 batches per XCD
    const int b   = lbid >> 3;
    const int tii = (lbid >> 2) & 1;   // n-half (A rows 128)
    const int tj  = lbid & 3;          // m-chunk (B rows 64)

    const int t  = threadIdx.x;
    const int wv = t >> 6, lane = t & 63;

    // Staging roles (wave-uniform): waves 0-3 stage A (both arrays,
    // weighted), waves 4-7 stage B (one array each). Octet sits in thread
    // bits 4-6 -> 4 octets per wave -> conflict-free b128 tile writes.
    const bool isA  = (t < 256);
    const int  u    = t & 255;
    const int  oct  = (u >> 4) & 7;                      // s-octet in K-half
    const int  nqA  = (u & 15) | ((u >> 7) << 4);        // 0..31 (A rows /4)
    const int  nqB  = u & 15;                            // 0..15 (B rows /4)
    const int  arrB = u >> 7;                            // B array 0=r 1=i

    const size_t bb = (size_t)b * S * N;
    const float* srcAR = R + bb + tii * 128 + nqA * 4;
    const float* srcAI = I + bb + tii * 128 + nqA * 4;
    const float* srcB  = (arrB ? I : R) + bb + tj * 64 + nqB * 4;
    const float* Wb    = W + b * S;

    // ---- issue H0 loads (s = oct*8 + 0..7) ----
    float4 L0[8], L1[8];
    if (isA) {
        #pragma unroll
        for (int s = 0; s < 8; ++s) {
            const size_t ro = (size_t)(oct * 8 + s) * N;
            L0[s] = *(const float4*)&srcAR[ro];
            L1[s] = *(const float4*)&srcAI[ro];
        }
    } else {
        #pragma unroll
        for (int s = 0; s < 8; ++s)
            L0[s] = *(const float4*)&srcB[(size_t)(oct * 8 + s) * N];
    }

    float w0[8], w1[8];
    if (isA) {
        const float4 a0 = *(const float4*)&Wb[oct * 8];
        const float4 a1 = *(const float4*)&Wb[oct * 8 + 4];
        const float4 a2 = *(const float4*)&Wb[64 + oct * 8];
        const float4 a3 = *(const float4*)&Wb[64 + oct * 8 + 4];
        w0[0]=a0.x; w0[1]=a0.y; w0[2]=a0.z; w0[3]=a0.w;
        w0[4]=a1.x; w0[5]=a1.y; w0[6]=a1.z; w0[7]=a1.w;
        w1[0]=a2.x; w1[1]=a2.y; w1[2]=a2.z; w1[3]=a2.w;
        w1[4]=a3.x; w1[5]=a3.y; w1[6]=a3.z; w1[7]=a3.w;
    }

    // ---- cvt + write H0 (chunk c = oct) ----
    if (isA) {
        #pragma unroll
        for (int j = 0; j < 4; ++j) {
            const int n    = nqA * 4 + j;
            const int slot = oct ^ ((n >> 1) & 7);
            F16x8 fr, fi;
            #pragma unroll
            for (int k = 0; k < 4; ++k) {
                fr.h2[k] = __floats2half2_rn(((const float*)&L0[2*k])[j]   * w0[2*k],
                                             ((const float*)&L0[2*k+1])[j] * w0[2*k+1]);
                fi.h2[k] = __floats2half2_rn(((const float*)&L1[2*k])[j]   * w0[2*k],
                                             ((const float*)&L1[2*k+1])[j] * w0[2*k+1]);
            }
            *(f16x8*)&AW[0][n][slot * 8] = fr.v;
            *(f16x8*)&AW[1][n][slot * 8] = fi.v;
        }
    } else {
        #pragma unroll
        for (int j = 0; j < 4; ++j) {
            const int n    = nqB * 4 + j;
            const int slot = oct ^ ((n >> 1) & 7);
            F16x8 f;
            #pragma unroll
            for (int k = 0; k < 4; ++k)
                f.h2[k] = __floats2half2_rn(((const float*)&L0[2*k])[j],
                                            ((const float*)&L0[2*k+1])[j]);
            *(f16x8*)&Bt[arrB][n][slot * 8] = f.v;
        }
    }

    // ---- issue H1 loads (s = 64 + oct*8 + 0..7); fly during MFMA H0 ----
    float4 M0[8], M1[8];
    if (isA) {
        #pragma unroll
        for (int s = 0; s < 8; ++s) {
            const size_t ro = (size_t)(64 + oct * 8 + s) * N;
            M0[s] = *(const float4*)&srcAR[ro];
            M1[s] = *(const float4*)&srcAI[ro];
        }
    } else {
        #pragma unroll
        for (int s = 0; s < 8; ++s)
            M0[s] = *(const float4*)&srcB[(size_t)(64 + oct * 8 + s) * N];
    }

    __syncthreads();   // H0 tiles visible

    // ---- MFMA geometry: wave = 32(n) x 32(m); grid 4 x 2 of waves ----
    const int wn = (wv & 3) * 32;
    const int wm = (wv >> 2) * 32;
    const int fr16 = lane & 15, kb = lane >> 4;
    const int ra0 = wn + fr16;        const int sa0 = (ra0 >> 1) & 7;
    const int ra1 = wn + 16 + fr16;   const int sa1 = (ra1 >> 1) & 7;
    const int rb0 = wm + fr16;        const int sb0 = (rb0 >> 1) & 7;
    const int rb1 = wm + 16 + fr16;   const int sb1 = (rb1 >> 1) & 7;

    f32x4 accR[2][2] = {}, accA[2][2] = {}, accB[2][2] = {};
    f16x8 awr[2], awi[2];

#define LOAD_A(ks) { const int K = (ks) * 4 + kb;                            \
        awr[0] = *(const f16x8*)&AW[0][ra0][(K ^ sa0) * 8];                  \
        awi[0] = *(const f16x8*)&AW[1][ra0][(K ^ sa0) * 8];                  \
        awr[1] = *(const f16x8*)&AW[0][ra1][(K ^ sa1) * 8];                  \
        awi[1] = *(const f16x8*)&AW[1][ra1][(K ^ sa1) * 8]; }
#define STEP(ks, ms) { const int K = (ks) * 4 + kb;                          \
        const int rbx = (ms) ? rb1 : rb0;                                    \
        const int cb  = (K ^ ((ms) ? sb1 : sb0)) * 8;                        \
        const f16x8 br = *(const f16x8*)&Bt[0][rbx][cb];                     \
        const f16x8 bi = *(const f16x8*)&Bt[1][rbx][cb];                     \
        accR[0][ms] = MFMA16(awr[0], br, accR[0][ms]);                       \
        accR[0][ms] = MFMA16(awi[0], bi, accR[0][ms]);                       \
        accA[0][ms] = MFMA16(awi[0], br, accA[0][ms]);                       \
        accB[0][ms] = MFMA16(awr[0], bi, accB[0][ms]);                       \
        accR[1][ms] = MFMA16(awr[1], br, accR[1][ms]);                       \
        accR[1][ms] = MFMA16(awi[1], bi, accR[1][ms]);                       \
        accA[1][ms] = MFMA16(awi[1], br, accA[1][ms]);                       \
        accB[1][ms] = MFMA16(awr[1], bi, accB[1][ms]); }

    // ---- MFMA over H0 (ks = 0,1) ----
    __builtin_amdgcn_s_setprio(1);
    LOAD_A(0); STEP(0, 0); STEP(0, 1);
    LOAD_A(1); STEP(1, 0); STEP(1, 1);
    __builtin_amdgcn_s_setprio(0);

    // ---- cvt + write H1 (chunk c = 8+oct; slots disjoint via bit 3) ----
    if (isA) {
        #pragma unroll
        for (int j = 0; j < 4; ++j) {
            const int n    = nqA * 4 + j;
            const int slot = (8 + oct) ^ ((n >> 1) & 7);
            F16x8 fr, fi;
            #pragma unroll
            for (int k = 0; k < 4; ++k) {
                fr.h2[k] = __floats2half2_rn(((const float*)&M0[2*k])[j]   * w1[2*k],
                                             ((const float*)&M0[2*k+1])[j] * w1[2*k+1]);
                fi.h2[k] = __floats2half2_rn(((const float*)&M1[2*k])[j]   * w1[2*k],
                                             ((const float*)&M1[2*k+1])[j] * w1[2*k+1]);
            }
            *(f16x8*)&AW[0][n][slot * 8] = fr.v;
            *(f16x8*)&AW[1][n][slot * 8] = fi.v;
        }
    } else {
        #pragma unroll
        for (int j = 0; j < 4; ++j) {
            const int n    = nqB * 4 + j;
            const int slot = (8 + oct) ^ ((n >> 1) & 7);
            F16x8 f;
            #pragma unroll
            for (int k = 0; k < 4; ++k)
                f.h2[k] = __floats2half2_rn(((const float*)&M0[2*k])[j],
                                            ((const float*)&M0[2*k+1])[j]);
            *(f16x8*)&Bt[arrB][n][slot * 8] = f.v;
        }
    }

    __syncthreads();   // H1 tiles visible

    const int nnb = tii * 128 + wn + kb * 4;

#define STORE_MS(ms) {                                                       \
        const int mm = tj * 64 + wm + (ms) * 16 + fr16;                      \
        _Pragma("unroll")                                                    \
        for (int ns = 0; ns < 2; ++ns) {                                     \
            const int nn = nnb + ns * 16;                                    \
            _Pragma("unroll")                                                \
            for (int r = 0; r < 4; ++r) {                                    \
                const size_t o = ((size_t)b * N + nn + r) * N + mm;          \
                Or[o] = accR[ns][ms][r];                                     \
                Oi[o] = accA[ns][ms][r] - accB[ns][ms][r];                   \
            }                                                                \
        } }

    // ---- MFMA over H1 (ks = 2,3) with ms-split tail stores ----
    __builtin_amdgcn_s_setprio(1);
    LOAD_A(2); STEP(2, 0); STEP(2, 1);
    LOAD_A(3); STEP(3, 0);
    __builtin_amdgcn_s_setprio(0);
    STORE_MS(0);                 // HBM drain starts while ms=1 finishes
    __builtin_amdgcn_s_setprio(1);
    STEP(3, 1);
    __builtin_amdgcn_s_setprio(0);
    STORE_MS(1);
}

extern "C" void kernel_launch(void* const* d_in, const int* in_sizes, int n_in,
                              void* d_out, int out_size, void* d_ws, size_t ws_size,
                              hipStream_t stream) {
    const float* R = (const float*)d_in[0];
    const float* I = (const float*)d_in[1];
    const float* W = (const float*)d_in[2];
    float* Or = (float*)d_out;
    float* Oi = (float*)d_out + (size_t)B * N * N;

    ComplexMixture_71313636983193_kernel<<<dim3(256), dim3(512), 0, stream>>>(
        R, I, W, Or, Oi);
}

// Round 12
// 12.622 us; speedup vs baseline: 1.3889x; 1.3889x over previous
//
#include <hip/hip_runtime.h>
#include <hip/hip_fp16.h>

// ComplexMixture: B=32, S=128, N=256
// Or[b,n,m] = sum_s w[b,s]*(r[b,s,n]*r[b,s,m] + i[b,s,n]*i[b,s,m])
// Oi[b,n,m] = sum_s w[b,s]*(i[b,s,n]*r[b,s,m] - r[b,s,n]*i[b,s,m])
//
// R12 = R10 (proven 12.84) + counted-wait barriers (T4): __syncthreads()
// emits s_waitcnt vmcnt(0) before s_barrier, which was draining the B2
// prefetch loads at barrier 1 and tile-1's stores at barrier 2 — killing
// the intended overlap. Replace with lgkmcnt(0)-only + raw s_barrier
// (LDS deps are lgkm; B2 has its own buffer so no WAR; stores never read).
// Plus: tile-2 ks-outer (dedup A-frag reads), tile-1 stores interleaved
// with B2 cvt. Same proven swizzle slot = chunk ^ ((row>>1)&7), same
// geometry: 256 blocks x 512 thr, LDS 96 KB, XCD-grouped bid swizzle.

constexpr int B = 32, S = 128, N = 256;

typedef _Float16 f16x8 __attribute__((ext_vector_type(8)));
typedef float    f32x4 __attribute__((ext_vector_type(4)));

union F16x8 { f16x8 v; __half2 h2[4]; };

#define MFMA16(a, bv, c) __builtin_amdgcn_mfma_f32_16x16x32_f16((a), (bv), (c), 0, 0, 0)

// LDS-only barrier: waits this thread's ds ops, NOT vmem (loads/stores fly).
#define LBAR() {                                                             \
        __builtin_amdgcn_sched_barrier(0);                                   \
        asm volatile("s_waitcnt lgkmcnt(0)" ::: "memory");                   \
        __builtin_amdgcn_s_barrier();                                        \
        __builtin_amdgcn_sched_barrier(0); }

__global__ __launch_bounds__(512, 2) void ComplexMixture_71313636983193_kernel(
    const float* __restrict__ R, const float* __restrict__ I,
    const float* __restrict__ W, float* __restrict__ Or, float* __restrict__ Oi)
{
    // T[0..1] = w*r, w*i (A rows = n-chunk ti)
    // T[2..3] = r, i (B rows = m-chunk tj1);  T[4..5] = r, i (m-chunk tj2)
    // row x, logical chunk c (8 s) at slot c ^ ((x>>1)&7)
    __shared__ alignas(16) _Float16 T[6][64][128];   // 96 KB

    const int pb   = blockIdx.x;
    const int lbid = (pb & 7) * 32 + (pb >> 3);   // 4 batches per XCD
    const int b   = lbid >> 3;
    const int rem = lbid & 7;
    const int ti  = rem >> 1;          // A-side n-chunk
    const int uu  = rem & 1;
    const int tj1 = uu * 2, tj2 = uu * 2 + 1;   // the two B-side m-chunks

    const int t  = threadIdx.x;
    const int wv = t >> 6, lane = t & 63;

    // staging task: 512 = nquad(16) x octet(16) x arr(2)
    const int nquad = t & 15;          // n = nquad*4 + j
    const int octet = (t >> 4) & 15;   // s-octet 0..15 (full K)
    const int arr   = t >> 8;          // 0 = real, 1 = imag (wave-uniform)
    const int s0    = octet * 8;

    const size_t bb = (size_t)b * S * N;
    const float* base  = (arr ? I : R) + bb + nquad * 4;
    const float* srcA  = base + ti  * 64;
    const float* srcB1 = base + tj1 * 64;
    const float* srcB2 = base + tj2 * 64;
    const float* Wb = W + b * S;

    // ---- issue A + B1 loads (8 rows of 4 n each) ----
    float4 fA[8], fB1[8];
    #pragma unroll
    for (int s = 0; s < 8; ++s)
        fA[s] = *(const float4*)&srcA[(size_t)(s0 + s) * N];
    #pragma unroll
    for (int s = 0; s < 8; ++s)
        fB1[s] = *(const float4*)&srcB1[(size_t)(s0 + s) * N];

    float w8[8];
    {
        const float4 a0 = *(const float4*)&Wb[s0];
        const float4 a1 = *(const float4*)&Wb[s0 + 4];
        w8[0]=a0.x; w8[1]=a0.y; w8[2]=a0.z; w8[3]=a0.w;
        w8[4]=a1.x; w8[5]=a1.y; w8[6]=a1.z; w8[7]=a1.w;
    }

    // ---- cvt + write A (weighted) and B1 ----
    #pragma unroll
    for (int j = 0; j < 4; ++j) {
        const int n    = nquad * 4 + j;
        const int slot = octet ^ ((n >> 1) & 7);
        F16x8 fa, fb;
        #pragma unroll
        for (int k = 0; k < 4; ++k) {
            fa.h2[k] = __floats2half2_rn(((const float*)&fA[2*k])[j]   * w8[2*k],
                                         ((const float*)&fA[2*k+1])[j] * w8[2*k+1]);
            fb.h2[k] = __floats2half2_rn(((const float*)&fB1[2*k])[j],
                                         ((const float*)&fB1[2*k+1])[j]);
        }
        *(f16x8*)&T[arr][n][slot * 8]     = fa.v;
        *(f16x8*)&T[2 + arr][n][slot * 8] = fb.v;
    }

    // ---- issue B2 loads; they fly across the (lgkm-only) barrier ----
    float4 fB2[8];
    #pragma unroll
    for (int s = 0; s < 8; ++s)
        fB2[s] = *(const float4*)&srcB2[(size_t)(s0 + s) * N];

    LBAR();   // A, B1 visible; B2 loads still in flight

    // ---- MFMA geometry (R9-proven): wave = 16(n) x 32(m) sub-tile ----
    const int wn = (wv & 3) * 16;
    const int wm = (wv >> 2) * 32;
    const int fr16 = lane & 15, kb = lane >> 4;
    const int ra  = wn + fr16;          const int sa  = (ra  >> 1) & 7;
    const int rb0 = wm + fr16;          const int sb0 = (rb0 >> 1) & 7;
    const int rb1 = wm + 16 + fr16;     const int sb1 = (rb1 >> 1) & 7;

    f16x8 awr, awi;

#define LOAD_A(ks) { const int ca = (((ks) * 4 + kb) ^ sa) * 8;              \
        awr = *(const f16x8*)&T[0][ra][ca];                                  \
        awi = *(const f16x8*)&T[1][ra][ca]; }
#define STEP_B(TB, ks, ms, aR, aA, aB) { const int K = (ks) * 4 + kb;        \
        const int rb = (ms) ? rb1 : rb0;                                     \
        const int cb = (K ^ ((ms) ? sb1 : sb0)) * 8;                         \
        const f16x8 br = *(const f16x8*)&T[TB][rb][cb];                      \
        const f16x8 bi = *(const f16x8*)&T[(TB) + 1][rb][cb];                \
        aR[ms] = MFMA16(awr, br, aR[ms]);                                    \
        aR[ms] = MFMA16(awi, bi, aR[ms]);                                    \
        aA[ms] = MFMA16(awi, br, aA[ms]);                                    \
        aB[ms] = MFMA16(awr, bi, aB[ms]); }

    const int n0 = ti * 64;
    const int nn = n0 + wn + kb * 4;

#define STORE_MS(TJ, ms, aR, aA, aB) {                                       \
        const int mm = (TJ) * 64 + wm + (ms) * 16 + fr16;                    \
        _Pragma("unroll")                                                    \
        for (int r = 0; r < 4; ++r) {                                        \
            const size_t o = ((size_t)b * N + nn + r) * N + mm;              \
            Or[o] = aR[ms][r];                                               \
            Oi[o] = aA[ms][r] - aB[ms][r];                                   \
        } }

#define B2CVT(j) {                                                           \
        const int n    = nquad * 4 + (j);                                    \
        const int slot = octet ^ ((n >> 1) & 7);                             \
        F16x8 fb;                                                            \
        _Pragma("unroll")                                                    \
        for (int k = 0; k < 4; ++k)                                          \
            fb.h2[k] = __floats2half2_rn(((const float*)&fB2[2*k])[(j)],     \
                                         ((const float*)&fB2[2*k+1])[(j)]);  \
        *(f16x8*)&T[4 + arr][n][slot * 8] = fb.v; }

    // ---- tile 1: full-K MFMA (B2 loads draining underneath) ----
    f32x4 a1R[2] = {}, a1A[2] = {}, a1B[2] = {};
    __builtin_amdgcn_s_setprio(1);
    LOAD_A(0); STEP_B(2, 0, 0, a1R, a1A, a1B); STEP_B(2, 0, 1, a1R, a1A, a1B);
    LOAD_A(1); STEP_B(2, 1, 0, a1R, a1A, a1B); STEP_B(2, 1, 1, a1R, a1A, a1B);
    LOAD_A(2); STEP_B(2, 2, 0, a1R, a1A, a1B); STEP_B(2, 2, 1, a1R, a1A, a1B);
    LOAD_A(3); STEP_B(2, 3, 0, a1R, a1A, a1B); STEP_B(2, 3, 1, a1R, a1A, a1B);
    __builtin_amdgcn_s_setprio(0);

    // ---- tile1 stores interleaved with B2 cvt+write ----
    STORE_MS(tj1, 0, a1R, a1A, a1B);
    B2CVT(0); B2CVT(1);
    STORE_MS(tj1, 1, a1R, a1A, a1B);
    B2CVT(2); B2CVT(3);

    LBAR();   // B2 visible; tile1 stores still in flight

    // ---- tile 2: ks-outer (A-frags read once), ms-split tail ----
    f32x4 a2R[2] = {}, a2A[2] = {}, a2B[2] = {};
    __builtin_amdgcn_s_setprio(1);
    LOAD_A(0); STEP_B(4, 0, 0, a2R, a2A, a2B); STEP_B(4, 0, 1, a2R, a2A, a2B);
    LOAD_A(1); STEP_B(4, 1, 0, a2R, a2A, a2B); STEP_B(4, 1, 1, a2R, a2A, a2B);
    LOAD_A(2); STEP_B(4, 2, 0, a2R, a2A, a2B); STEP_B(4, 2, 1, a2R, a2A, a2B);
    LOAD_A(3); STEP_B(4, 3, 0, a2R, a2A, a2B);
    __builtin_amdgcn_s_setprio(0);
    STORE_MS(tj2, 0, a2R, a2A, a2B);   // drain starts while ms=1 finishes
    __builtin_amdgcn_s_setprio(1);
    STEP_B(4, 3, 1, a2R, a2A, a2B);
    __builtin_amdgcn_s_setprio(0);
    STORE_MS(tj2, 1, a2R, a2A, a2B);
}

extern "C" void kernel_launch(void* const* d_in, const int* in_sizes, int n_in,
                              void* d_out, int out_size, void* d_ws, size_t ws_size,
                              hipStream_t stream) {
    const float* R = (const float*)d_in[0];
    const float* I = (const float*)d_in[1];
    const float* W = (const float*)d_in[2];
    float* Or = (float*)d_out;
    float* Oi = (float*)d_out + (size_t)B * N * N;

    ComplexMixture_71313636983193_kernel<<<dim3(256), dim3(512), 0, stream>>>(
        R, I, W, Or, Oi);
}